// Round 8
// baseline (456.725 us; speedup 1.0000x reference)
//
#include <hip/hip_runtime.h>
#include <hip/hip_fp16.h>

// Pipeline (all fp16 MFMA, f32 accum):
//   cvt Wq,Wk,Wv ; cvt e -> slot1 ; k=e@Wk^T+bk -> slot2 (proj256)
//   cvt b -> slot1 ; q=b@Wq^T+bq -> slot3 ; v=b@Wv^T+bv -> slot4 [BT,608] (proj256)
//   attn=tanh(q@k^T) -> slot1, batched (128^2 3-stage kernel)
//   out=attn@v^T -> f32 d_out, batched
//
// proj256: m201-class 256x256 tile, BK=64, 8 waves (2M x 4N), wave tile 128x64,
// LDS 128 KiB = {A,B} x {par0,par1} x {klo,khi} slots of 256rows x 32cols fp16.
// 4 phases per K-tile: (klo,Mlo),(klo,Mhi),(khi,Mlo),(khi,Mhi); each phase:
//   8 ds_read_b128 (frags) ; stage 1 half-tile (2 global_load_lds w=16) ;
//   s_barrier ; lgkmcnt(0) ; setprio(1) ; 16 MFMA ; setprio(0) ; s_barrier.
// Half-tile recycling: a slot is restaged exactly 2 phases after its last
// reader phase; the two-barrier phase structure orders write-after-read.
// vmcnt(4) once per K-tile in the last phase (before its pre-MFMA barrier):
// confirms tile t+1 landed; the barrier rendezvous publishes it to all waves.
// Slot swizzle (verified R6): chunk c of a slot holds row c>>2, col-chunk
// (c&3)^((c>>3)&3); read lane l row r: chunk r*4 + ((l>>4) ^ ((r>>1)&3)).
// Conflict-free ds_read_b128 + intact 64B-line write coalescing.

typedef _Float16 f16x8 __attribute__((ext_vector_type(8)));
typedef float f32x4 __attribute__((ext_vector_type(4)));

__global__ void cvt8_kernel(const float* __restrict__ src, _Float16* __restrict__ dst,
                            long long n8) {
    long long i = blockIdx.x * (long long)blockDim.x + threadIdx.x;
    const long long stride = gridDim.x * (long long)blockDim.x;
    for (; i < n8; i += stride) {
        const float4 f0 = ((const float4*)src)[2 * i];
        const float4 f1 = ((const float4*)src)[2 * i + 1];
        f16x8 h;
        h[0] = (_Float16)f0.x; h[1] = (_Float16)f0.y; h[2] = (_Float16)f0.z; h[3] = (_Float16)f0.w;
        h[4] = (_Float16)f1.x; h[5] = (_Float16)f1.y; h[6] = (_Float16)f1.z; h[7] = (_Float16)f1.w;
        ((f16x8*)dst)[i] = h;
    }
}

__device__ __forceinline__ void gload16(const _Float16* g, _Float16* l) {
    __builtin_amdgcn_global_load_lds(
        (const __attribute__((address_space(1))) unsigned int*)(g),
        (__attribute__((address_space(3))) unsigned int*)(l),
        16, 0, 0);
}

// ---------------- proj256: 256x256 / BK=64 / 8-wave 8-phase -----------------
__global__ __launch_bounds__(512, 2)
void proj256(const _Float16* __restrict__ A, const _Float16* __restrict__ Bt,
             const float* __restrict__ bias, _Float16* __restrict__ C,
             int M, int Nreal, int Nstore, int K,
             int lda, int ldb, int ldc, int nTileN)
{
    __shared__ __align__(16) _Float16 lds[65536];   // 128 KiB

    // bijective XCD chunking (m204)
    int bid = blockIdx.x;
    {
        const int nwg = gridDim.x;
        const int q8 = nwg >> 3, r8 = nwg & 7;
        const int xcd = bid & 7, loc = bid >> 3;
        bid = (xcd < r8 ? xcd * (q8 + 1) : r8 * (q8 + 1) + (xcd - r8) * q8) + loc;
    }
    const int tm = bid / nTileN, tn = bid - tm * nTileN;
    const int m0 = tm << 8, n0 = tn << 8;

    const int tid  = threadIdx.x;
    const int lane = tid & 63;
    const int wid  = tid >> 6;          // 0..7
    const int wm = wid >> 2;            // 0..1 : M-half (128 rows)
    const int wn = wid & 3;             // 0..3 : N-quarter (64 cols)

    // staging source (per thread, chunks tid and tid+512)
    const int cs = (((tid & 3) ^ ((tid >> 3) & 3)) << 3);   // swizzled col (hw)
    const int rl = tid >> 2;                                // 0..127
    const int rA0 = (m0 + rl       < M ? m0 + rl       : M - 1);
    const int rA1 = (m0 + rl + 128 < M ? m0 + rl + 128 : M - 1);
    const int rB0 = (n0 + rl       < Nreal ? n0 + rl       : Nreal - 1);
    const int rB1 = (n0 + rl + 128 < Nreal ? n0 + rl + 128 : Nreal - 1);
    const _Float16* pAr0 = A + (size_t)rA0 * lda + cs;
    const _Float16* pAr1 = A + (size_t)rA1 * lda + cs;
    const _Float16* pBr0 = Bt + (size_t)rB0 * ldb + cs;
    const _Float16* pBr1 = Bt + (size_t)rB1 * ldb + cs;

    // fragment read bases (hw offsets within a slot region)
    const int rr = lane & 15;
    const int hh = lane >> 4;                 // 0..3 (8-col k-chunk)
    const int sw = (rr >> 1) & 3;
    const int fAbase = (wm * 128 + rr) * 32 + ((hh ^ sw) << 3);           // + mh*2048 + mi*512
    const int fBbase = 32768 + (wn * 64 + rr) * 32 + ((hh ^ sw) << 3);    // + nj*512

    const f32x4 z4 = {0.f, 0.f, 0.f, 0.f};
    f32x4 acc[8][4];
#pragma unroll
    for (int i = 0; i < 8; ++i)
#pragma unroll
        for (int j = 0; j < 4; ++j) acc[i][j] = z4;

    const int nt = K >> 6;                    // K-tiles of 64 (even, >= 4)

    // STAGE one half-tile: operand slot (par,kh) <- K window of tile tt
#define STAGE_A(par, kh, tt)                                              \
    do {                                                                  \
        const int sb_ = ((par) * 2 + (kh)) * 8192;                        \
        const int ko_ = ((tt) << 6) + ((kh) << 5);                        \
        gload16(pAr0 + ko_, lds + sb_ + tid * 8);                         \
        gload16(pAr1 + ko_, lds + sb_ + (512 + tid) * 8);                 \
    } while (0)
#define STAGE_B(par, kh, tt)                                              \
    do {                                                                  \
        const int sb_ = 32768 + ((par) * 2 + (kh)) * 8192;                \
        const int ko_ = ((tt) << 6) + ((kh) << 5);                        \
        gload16(pBr0 + ko_, lds + sb_ + tid * 8);                         \
        gload16(pBr1 + ko_, lds + sb_ + (512 + tid) * 8);                 \
    } while (0)

#define PHASE(par, kh, mh, ...)                                                      \
    do {                                                                             \
        const int sb_ = ((par) * 2 + (kh)) * 8192;                                   \
        f16x8 a_[4], b_[4];                                                          \
        _Pragma("unroll")                                                            \
        for (int mi = 0; mi < 4; ++mi)                                               \
            a_[mi] = *(const f16x8*)(lds + sb_ + fAbase + (mh) * 2048 + mi * 512);   \
        _Pragma("unroll")                                                            \
        for (int nj = 0; nj < 4; ++nj)                                               \
            b_[nj] = *(const f16x8*)(lds + sb_ + fBbase + nj * 512);                 \
        __VA_ARGS__;                                                                 \
        __builtin_amdgcn_s_barrier();                                                \
        asm volatile("s_waitcnt lgkmcnt(0)" ::: "memory");                           \
        __builtin_amdgcn_sched_barrier(0);                                           \
        __builtin_amdgcn_s_setprio(1);                                               \
        _Pragma("unroll")                                                            \
        for (int mi = 0; mi < 4; ++mi)                                               \
            _Pragma("unroll")                                                        \
            for (int nj = 0; nj < 4; ++nj)                                           \
                acc[(mh) * 4 + mi][nj] = __builtin_amdgcn_mfma_f32_16x16x32_f16(     \
                    a_[mi], b_[nj], acc[(mh) * 4 + mi][nj], 0, 0, 0);                \
        __builtin_amdgcn_s_setprio(0);                                               \
        __builtin_amdgcn_s_barrier();                                                \
    } while (0)

    // TILE t (parity par): 4 phases; stages refill slots freed 2 phases ago.
    // vmcnt(4) in last phase confirms tile t+1 (its halves are older than the
    // 4 newest loads = this tile's p3/p4 stages); tail uses vmcnt(0).
#define TILE(par, t)                                                                  \
    do {                                                                              \
        PHASE(par, 0, 0, if ((t) >= 1 && (t) + 1 < nt) STAGE_A((par) ^ 1, 1, (t) + 1)); \
        PHASE(par, 0, 1, if ((t) >= 1 && (t) + 1 < nt) STAGE_B((par) ^ 1, 1, (t) + 1)); \
        PHASE(par, 1, 0, if ((t) + 2 < nt) STAGE_A((par), 0, (t) + 2));               \
        PHASE(par, 1, 1,                                                              \
              if ((t) + 2 < nt) {                                                     \
                  STAGE_B((par), 0, (t) + 2);                                         \
                  asm volatile("s_waitcnt vmcnt(4)" ::: "memory");                    \
              } else if ((t) + 1 < nt) {                                              \
                  asm volatile("s_waitcnt vmcnt(0)" ::: "memory");                    \
              });                                                                     \
    } while (0)

    // prologue: tiles 0 and 1 fully staged (16 loads); tile 0 = oldest 8
    STAGE_A(0, 0, 0); STAGE_A(0, 1, 0); STAGE_B(0, 0, 0); STAGE_B(0, 1, 0);
    STAGE_A(1, 0, 1); STAGE_A(1, 1, 1); STAGE_B(1, 0, 1); STAGE_B(1, 1, 1);
    asm volatile("s_waitcnt vmcnt(8)" ::: "memory");
    __builtin_amdgcn_s_barrier();

    for (int t = 0; t < nt; t += 2) {
        TILE(0, t);
        TILE(1, t + 1);
    }

#undef STAGE_A
#undef STAGE_B
#undef PHASE
#undef TILE

    // epilogue: bias -> store f16 (zero padded cols [Nreal, Nstore))
    const int cr0 = (lane >> 4) << 2;
    const int cc  = lane & 15;
#pragma unroll
    for (int q = 0; q < 8; ++q) {
        const int grb = m0 + wm * 128 + (q >> 2) * 64 + (q & 3) * 16 + cr0;
#pragma unroll
        for (int nj = 0; nj < 4; ++nj) {
            const int gc = n0 + wn * 64 + nj * 16 + cc;
            if (gc >= Nstore) continue;
            const bool real = gc < Nreal;
            const float bb = real ? bias[gc] : 0.f;
#pragma unroll
            for (int r = 0; r < 4; ++r) {
                const int gr = grb + r;
                if (gr >= M) continue;
                const float x = real ? (acc[q][nj][r] + bb) : 0.f;
                C[(size_t)gr * ldc + gc] = (_Float16)x;
            }
        }
    }
}

// -------- batched 128x128 / BK=32 / 3-stage kernel (R7, unchanged) ----------
template<bool TANH, bool OUT_F16, bool BIAS, int MODE>
__global__ __launch_bounds__(256)
void gemm_nt_f16(const _Float16* __restrict__ A, const _Float16* __restrict__ Bt,
                 const float* __restrict__ bias, void* __restrict__ Cp,
                 int M, int Nreal, int Nstore, int K,
                 int lda, int ldb, int ldc, int nTileN, int nTiles,
                 long long sA, long long sB, long long sC)
{
    __shared__ __align__(16) _Float16 lds[3 * 8192];

    int bid = blockIdx.x;
    int z, tm, tn;
    if (MODE == 0) {
        const int nwg = gridDim.x;
        const int q8 = nwg >> 3, r8 = nwg & 7;
        const int xcd = bid & 7, loc = bid >> 3;
        bid = (xcd < r8 ? xcd * (q8 + 1) : r8 * (q8 + 1) + (xcd - r8) * q8) + loc;
        z = 0;
        tm = bid / nTileN; tn = bid - tm * nTileN;
    } else {
        const int xcd = bid & 7, idx = bid >> 3;
        const int g = idx / nTiles, tile = idx - g * nTiles;
        z = g * 8 + xcd;
        tm = tile / nTileN; tn = tile - tm * nTileN;
    }
    const int m0 = tm << 7, n0 = tn << 7;

    const _Float16* Az = A + (size_t)z * sA;
    const _Float16* Bz = Bt + (size_t)z * sB;

    const int tid = threadIdx.x;
    const int lane = tid & 63;
    const int wid = tid >> 6;
    const int wm = wid >> 1, wn = wid & 1;

    const int r0 = tid >> 2;
    const int c0 = (((tid & 3) ^ ((tid >> 3) & 3)) << 3);
    const int rA0 = (m0 + r0      < M ? m0 + r0      : M - 1);
    const int rA1 = (m0 + r0 + 64 < M ? m0 + r0 + 64 : M - 1);
    const int rB0 = (n0 + r0      < Nreal ? n0 + r0      : Nreal - 1);
    const int rB1 = (n0 + r0 + 64 < Nreal ? n0 + r0 + 64 : Nreal - 1);
    const _Float16* pA0 = Az + (size_t)rA0 * lda + c0;
    const _Float16* pA1 = Az + (size_t)rA1 * lda + c0;
    const _Float16* pB0 = Bz + (size_t)rB0 * ldb + c0;
    const _Float16* pB1 = Bz + (size_t)rB1 * ldb + c0;

    const int o0 = tid * 8, o1 = (tid + 256) * 8;

    const int rr = lane & 15;
    const int hh = lane >> 4;
    const int sw = (rr >> 1) & 3;
    const int fAo = ((wm * 64 + rr) * 4 + (hh ^ sw)) * 8;
    const int fBo = ((wn * 64 + rr) * 4 + (hh ^ sw)) * 8;

    const f32x4 z4 = {0.f, 0.f, 0.f, 0.f};
    f32x4 acc[4][4];
#pragma unroll
    for (int i = 0; i < 4; ++i)
#pragma unroll
        for (int j = 0; j < 4; ++j) acc[i][j] = z4;

    const int nt = K >> 5;

#define STAGE(si, kt)                                              \
    do {                                                           \
        _Float16* base_ = lds + (si) * 8192;                       \
        const int ko_ = (kt) << 5;                                 \
        gload16(pA0 + ko_, base_ + o0);                            \
        gload16(pA1 + ko_, base_ + o1);                            \
        gload16(pB0 + ko_, base_ + 4096 + o0);                     \
        gload16(pB1 + ko_, base_ + 4096 + o1);                     \
    } while (0)

#define COMPUTE(si)                                                            \
    do {                                                                       \
        const _Float16* cA_ = lds + (si) * 8192;                               \
        const _Float16* cB_ = cA_ + 4096;                                      \
        f16x8 a_[4], b_[4];                                                    \
        _Pragma("unroll")                                                      \
        for (int mi = 0; mi < 4; ++mi) a_[mi] = *(const f16x8*)(cA_ + fAo + mi * 512); \
        _Pragma("unroll")                                                      \
        for (int ni = 0; ni < 4; ++ni) b_[ni] = *(const f16x8*)(cB_ + fBo + ni * 512); \
        _Pragma("unroll")                                                      \
        for (int mi = 0; mi < 4; ++mi)                                         \
            _Pragma("unroll")                                                  \
            for (int ni = 0; ni < 4; ++ni)                                     \
                acc[mi][ni] = __builtin_amdgcn_mfma_f32_16x16x32_f16(          \
                    a_[mi], b_[ni], acc[mi][ni], 0, 0, 0);                     \
    } while (0)

    STAGE(0, 0);
    STAGE(1, 1);

    for (int j = 0; j < nt - 1; ++j) {
        asm volatile("s_waitcnt vmcnt(4)" ::: "memory");
        __builtin_amdgcn_s_barrier();
        __builtin_amdgcn_sched_barrier(0);
        if (j + 2 < nt) STAGE((j + 2) % 3, j + 2);
        COMPUTE(j % 3);
    }
    asm volatile("s_waitcnt vmcnt(0)" ::: "memory");
    __builtin_amdgcn_s_barrier();
    __builtin_amdgcn_sched_barrier(0);
    COMPUTE((nt - 1) % 3);

#undef STAGE
#undef COMPUTE

    const int cr0 = (lane >> 4) << 2;
    const int cc = lane & 15;
    float*    Cf = (float*)Cp    + (size_t)z * sC;
    _Float16* Ch = (_Float16*)Cp + (size_t)z * sC;
#pragma unroll
    for (int mi = 0; mi < 4; ++mi) {
#pragma unroll
        for (int ni = 0; ni < 4; ++ni) {
            const int gc = n0 + wn * 64 + ni * 16 + cc;
            if (gc >= Nstore) continue;
            const bool real = gc < Nreal;
            float bb = 0.f;
            if (BIAS) bb = real ? bias[gc] : 0.f;
#pragma unroll
            for (int r = 0; r < 4; ++r) {
                const int gr = m0 + wm * 64 + mi * 16 + cr0 + r;
                if (gr >= M) continue;
                float x = real ? (acc[mi][ni][r] + bb) : 0.f;
                if (TANH) x = tanhf(x);
                if (OUT_F16) Ch[(size_t)gr * ldc + gc] = (_Float16)x;
                else         Cf[(size_t)gr * ldc + gc] = x;
            }
        }
    }
}

extern "C" void kernel_launch(void* const* d_in, const int* in_sizes, int n_in,
                              void* d_out, int out_size, void* d_ws, size_t ws_size,
                              hipStream_t stream)
{
    const float* b  = (const float*)d_in[0];
    const float* e  = (const float*)d_in[1];
    const float* Wq = (const float*)d_in[2];
    const float* bq = (const float*)d_in[3];
    const float* Wk = (const float*)d_in[4];
    const float* bk = (const float*)d_in[5];
    const float* Wv = (const float*)d_in[6];
    const float* bv = (const float*)d_in[7];
    float* out = (float*)d_out;

    const int BT = 36928, D = 768, T = 577, S = 577, Sp = 608;

    _Float16* Wq_h  = (_Float16*)d_ws;
    _Float16* Wk_h  = Wq_h + 589824;
    _Float16* Wv_h  = Wk_h + 589824;
    _Float16* slot1 = Wv_h + 443136;                 // e_h -> b_h -> at_h
    _Float16* slot2 = slot1 + (size_t)BT * D;        // k_h
    _Float16* slot3 = slot2 + (size_t)BT * D;        // q_h
    _Float16* slot4 = slot3 + (size_t)BT * D;        // v_h [BT,608]

    cvt8_kernel<<<288, 256, 0, stream>>>(Wq, Wq_h, 73728);
    cvt8_kernel<<<288, 256, 0, stream>>>(Wk, Wk_h, 73728);
    cvt8_kernel<<<217, 256, 0, stream>>>(Wv, Wv_h, 55392);

    // e -> fp16
    cvt8_kernel<<<2048, 256, 0, stream>>>(e, slot1, 3545088);
    // k = e@Wk^T + bk   [BT,768]   (145 M-tiles x 3 N-tiles)
    proj256<<<dim3(435, 1, 1), 512, 0, stream>>>(
        slot1, Wk_h, bk, slot2, BT, D, D, D, D, D, D, 3);
    // b -> fp16 (e_h dead)
    cvt8_kernel<<<2048, 256, 0, stream>>>(b, slot1, 3545088);
    // q = b@Wq^T + bq   [BT,768]
    proj256<<<dim3(435, 1, 1), 512, 0, stream>>>(
        slot1, Wq_h, bq, slot3, BT, D, D, D, D, D, D, 3);
    // v = b@Wv^T + bv   [BT,608] (cols 577..607 zeroed)
    proj256<<<dim3(435, 1, 1), 512, 0, stream>>>(
        slot1, Wv_h, bv, slot4, BT, S, Sp, D, D, D, Sp, 3);
    // attn = tanh(q@k^T) -> slot1 (b_h dead)  batched [64][577,608]
    gemm_nt_f16<true, true, false, 1><<<dim3(1600, 1, 1), 256, 0, stream>>>(
        slot3, slot2, nullptr, slot1, T, S, Sp, D, D, D, Sp, 5, 25,
        (long long)T * D, (long long)T * D, (long long)T * Sp);
    // out = attn@v^T   batched [64][577,577] f32, K=608 (pads zero)
    gemm_nt_f16<false, false, false, 1><<<dim3(1600, 1, 1), 256, 0, stream>>>(
        slot1, slot4, nullptr, out, T, T, T, Sp, Sp, Sp, T, 5, 25,
        (long long)T * Sp, (long long)T * Sp, (long long)T * T);
}